// Round 12
// baseline (80.347 us; speedup 1.0000x reference)
//
#include <hip/hip_runtime.h>
#include <hip/hip_bf16.h>

typedef float f32x4 __attribute__((ext_vector_type(4)));
typedef float f32x16 __attribute__((ext_vector_type(16)));
typedef short bf16x8 __attribute__((ext_vector_type(8)));

#define MFMA16(A,B,C) __builtin_amdgcn_mfma_f32_16x16x32_bf16(A,B,C,0,0,0)
#define MFMA32(A,B,C) __builtin_amdgcn_mfma_f32_32x32x16_bf16(A,B,C,0,0,0)

__device__ __forceinline__ unsigned short f2bf(float f) {
    union { float f; unsigned u; } x; x.f = f;
    return (unsigned short)((x.u + 0x7FFFu + ((x.u >> 16) & 1u)) >> 16);
}

__device__ __forceinline__ float bf2f(unsigned short u) {
    union { unsigned u; float f; } x; x.u = ((unsigned)u) << 16; return x.f;
}

__device__ __forceinline__ unsigned fbits(float f) {
    union { float f; unsigned u; } x; x.f = f; return x.u;
}

__device__ __forceinline__ f32x16 zero16() {
    f32x16 z;
#pragma unroll
    for (int i = 0; i < 16; ++i) z[i] = 0.f;
    return z;
}

typedef const __attribute__((address_space(1))) unsigned int* as1_t;
typedef __attribute__((address_space(3))) unsigned int* as3_t;
__device__ __forceinline__ void gl_lds16(const unsigned short* g, unsigned short* l) {
    __builtin_amdgcn_global_load_lds((as1_t)g, (as3_t)l, 16, 0, 0);
}

// ---------------- Kernel 1a: WT[n][k] = W_cat[k][n] bf16, coalesced reads -------
__global__ void prep_wt(const float* __restrict__ Wq, const float* __restrict__ Wk,
                        const float* __restrict__ Wv, unsigned short* __restrict__ WT) {
    int w = blockIdx.x % 3;
    int kt = blockIdx.x / 3;       // 0..31
    const float* src = (w == 0) ? Wq : (w == 1) ? Wk : Wv;
    int k0 = kt * 32;
#pragma unroll
    for (int j = 0; j < 16; ++j) {
        int idx = threadIdx.x + j * 256;       // 0..4095
        int r = idx >> 7, c = idx & 127;
        float v = src[(size_t)(k0 + r) * 128 + c];
        WT[(size_t)(w * 128 + c) * 1024 + k0 + r] = f2bf(v);
    }
}

// ---------------- Kernel 1b: Xb = bf16(X) ---------------------------------------
__global__ __launch_bounds__(256) void prep_x(const float* __restrict__ X,
                                              unsigned short* __restrict__ Xb) {
    int i = blockIdx.x * 256 + threadIdx.x;
#pragma unroll
    for (int r = 0; r < 8; ++r) {
        int idx = i + r * 262144;
        float4 x = ((const float4*)X)[idx];
        ushort4 p;
        p.x = f2bf(x.x); p.y = f2bf(x.y); p.z = f2bf(x.z); p.w = f2bf(x.w);
        ((ushort4*)Xb)[idx] = p;
    }
}

// ---------------- Kernel 2: QKV projection, 3-buffer counted-vmcnt pipeline -----
// BM=64 (grid 128,4 = 512 blocks). V keys stored permuted:
// storage pos = (s & ~15) | swap23(s & 15), so attn PV B-frags are single b128.
__global__ __launch_bounds__(256) void proj(const unsigned short* __restrict__ Xb,
        const unsigned short* __restrict__ WT, unsigned short* __restrict__ Qc,
        unsigned short* __restrict__ Kc, unsigned short* __restrict__ VT) {
    int tid = threadIdx.x;
    int w = tid >> 6, lane = tid & 63;
    int lr = lane & 15, lg = lane >> 4;
    int wr = w >> 1, wc = w & 1;              // 2x2 wave grid
    int m0 = blockIdx.x * 64;
    int n0 = blockIdx.y * 96;

    __shared__ __align__(16) unsigned short Ab[3][64 * 64];   // 8KB x3
    __shared__ __align__(16) unsigned short Bb[3][96 * 64];   // 12KB x3

    f32x4 acc[2][3];
#pragma unroll
    for (int i = 0; i < 2; ++i)
#pragma unroll
        for (int j = 0; j < 3; ++j) acc[i][j] = f32x4{0.f,0.f,0.f,0.f};

    int srow = lane >> 3;
    int sunit = lane & 7;
    const unsigned short* aSrc = Xb + (size_t)(m0 + srow) * 1024 + sunit * 8;
    const unsigned short* bSrc = WT + (size_t)(n0 + srow) * 1024 + sunit * 8;

    auto STAGE = [&](unsigned short* ad, unsigned short* bd, int st) {
        int kk = st * 64;
#pragma unroll
        for (int i = 0; i < 2; ++i) {
            int blk = w * 2 + i;              // 0..7
            gl_lds16(aSrc + (size_t)blk * 8 * 1024 + kk, ad + blk * 512);
        }
#pragma unroll
        for (int i = 0; i < 3; ++i) {
            int blk = w * 3 + i;              // 0..11
            gl_lds16(bSrc + (size_t)blk * 8 * 1024 + kk, bd + blk * 512);
        }
    };

    unsigned short *a0 = Ab[0], *a1 = Ab[1], *a2 = Ab[2];
    unsigned short *b0 = Bb[0], *b1 = Bb[1], *b2 = Bb[2];
    STAGE(a0, b0, 0);
    STAGE(a1, b1, 1);

    for (int st = 0; st < 16; ++st) {
        // wait only for tile st (next tile's 5 loads stay in flight)
        if (st < 15) asm volatile("s_waitcnt vmcnt(5)" ::: "memory");
        else         asm volatile("s_waitcnt vmcnt(0)" ::: "memory");
        __builtin_amdgcn_sched_barrier(0);
        __builtin_amdgcn_s_barrier();
        __builtin_amdgcn_sched_barrier(0);
        if (st + 2 < 16) STAGE(a2, b2, st + 2);

        const unsigned short* ab = a0;
        const unsigned short* bb = b0;
#pragma unroll
        for (int ksub = 0; ksub < 2; ++ksub) {
            int ko = ksub * 32 + lg * 8;
            bf16x8 af[2], bf[3];
#pragma unroll
            for (int mt = 0; mt < 2; ++mt)
                af[mt] = *(const bf16x8*)(ab + (wr * 32 + mt * 16 + lr) * 64 + ko);
#pragma unroll
            for (int nt = 0; nt < 3; ++nt)
                bf[nt] = *(const bf16x8*)(bb + (wc * 48 + nt * 16 + lr) * 64 + ko);
#pragma unroll
            for (int mt = 0; mt < 2; ++mt)
#pragma unroll
                for (int nt = 0; nt < 3; ++nt)
                    acc[mt][nt] = MFMA16(af[mt], bf[nt], acc[mt][nt]);
        }
        // rotate buffers
        unsigned short* t;
        t = a0; a0 = a1; a1 = a2; a2 = t;
        t = b0; b0 = b1; b1 = b2; b2 = t;
    }

    int b = m0 >> 12;
    int sbase = (m0 & 4095) + wr * 32;
#pragma unroll
    for (int nt = 0; nt < 3; ++nt) {
        int gcol = n0 + wc * 48 + nt * 16 + lr;     // 0..383
        int tensor = gcol >> 7;                     // 0=Q 1=K 2=V
#pragma unroll
        for (int mt = 0; mt < 2; ++mt) {
            int sloc = sbase + mt * 16 + 4 * lg;
            if (tensor == 2) {
                int vcol = gcol & 127;
                // key-permuted storage: 4-key group lg -> group swap(lg bits)
                int slocV = (sloc & ~15) | (((lg & 1) << 3) | ((lg >> 1) << 2));
                ushort4 pk;
                pk.x = f2bf(acc[mt][nt][0]); pk.y = f2bf(acc[mt][nt][1]);
                pk.z = f2bf(acc[mt][nt][2]); pk.w = f2bf(acc[mt][nt][3]);
                *(ushort4*)(VT + (size_t)(b * 128 + vcol) * 4096 + slocV) = pk;
            } else {
                int within = gcol & 127;
                int comp = within >> 6;
                int col64 = within & 63;
                float sc = (tensor == 0) ? 0.1803368801f : 1.0f;  // (1/8)*log2e in Q
                unsigned short* dst = (tensor == 0) ? Qc : Kc;
                size_t rowb = (size_t)(comp * 2 + b) * 4096 + sloc;
#pragma unroll
                for (int r = 0; r < 4; ++r)
                    dst[(rowb + r) * 64 + col64] = f2bf(acc[mt][nt][r] * sc);
            }
        }
    }
}

// ---------------- Kernel 3: flash attention, 2-buffer, 3 waves/SIMD -------------
// 32q/wave x 128v, swapped QK^T, in-register softmax (v_perm pack), VALU row-sums,
// key-permuted V (bank-conflict-free b128 PV reads). 8 k-splits, bf16 partials.
__global__ __launch_bounds__(256, 3) void attn(const unsigned short* __restrict__ Qc,
        const unsigned short* __restrict__ Kc, const unsigned short* __restrict__ VT,
        unsigned short* __restrict__ Opart, float* __restrict__ Lpart) {
    int tid = threadIdx.x;
    int wave = tid >> 6, lane = tid & 63;
    int l31 = lane & 31, hi = lane >> 5;
    int x7 = l31 & 7;
    int b = blockIdx.y;
    int comp = blockIdx.z >> 3, split = blockIdx.z & 7;
    int q0 = blockIdx.x * 128 + wave * 32;
    int kstart = split * 512;

    __shared__ __align__(16) unsigned short kb2[2][64 * 64];    // 8KB x2
    __shared__ __align__(16) unsigned short vb2[2][128 * 64];   // 16KB x2

    // Q B-frags: lane holds col q = q0+l31, d = j*16 + hi*8 + e
    const unsigned short* Qp = Qc + ((size_t)(comp * 2 + b) * 4096 + q0 + l31) * 64 + hi * 8;
    bf16x8 qB0 = *(const bf16x8*)(Qp);
    bf16x8 qB1 = *(const bf16x8*)(Qp + 16);
    bf16x8 qB2 = *(const bf16x8*)(Qp + 32);
    bf16x8 qB3 = *(const bf16x8*)(Qp + 48);

    f32x16 o[4];
#pragma unroll
    for (int i = 0; i < 4; ++i) o[i] = zero16();
    float lsum = 0.f;

    const unsigned short* kSrc = Kc + ((size_t)(comp * 2 + b) * 4096 + kstart
                                       + wave * 8 + (lane >> 3)) * 64
                                    + ((lane & 7) ^ (lane >> 3)) * 8;
    const unsigned short* vSrc = VT + ((size_t)b * 128 + (tid >> 3)) * 4096
                                    + kstart + ((lane & 7) ^ (lane >> 3)) * 8;

    auto STAGE = [&](unsigned short* kd, unsigned short* vd, int it) {
        const unsigned short* ks = kSrc + (size_t)it * 4096;
        gl_lds16(ks,        kd + wave * 512);
        gl_lds16(ks + 2048, kd + 2048 + wave * 512);
        const unsigned short* vs = vSrc + it * 64;
#pragma unroll
        for (int ri = 0; ri < 4; ++ri)
            gl_lds16(vs + (size_t)ri * 32 * 4096, vd + ri * 2048 + wave * 512);
    };

    unsigned short *k0 = kb2[0], *k1 = kb2[1];
    unsigned short *v0 = vb2[0], *v1 = vb2[1];
    STAGE(k0, v0, 0);

    for (int it = 0; it < 8; ++it) {
        // issue next tile into the other buffer (its loads fly across the barrier)
        if (it + 1 < 8) STAGE(k1, v1, it + 1);
        // wait for my 6 loads of the current tile only
        if (it + 1 < 8) asm volatile("s_waitcnt vmcnt(6)" ::: "memory");
        else            asm volatile("s_waitcnt vmcnt(0)" ::: "memory");
        __builtin_amdgcn_sched_barrier(0);
        __builtin_amdgcn_s_barrier();           // all waves' cur loads landed
        __builtin_amdgcn_sched_barrier(0);

        const unsigned short* kb = k0;
        const unsigned short* vb = v0;

        // S^T[k][q] for two 32-key half-tiles: A = K rows, B = Q cols
        f32x16 st0 = zero16(), st1 = zero16();
        __builtin_amdgcn_s_setprio(1);
#pragma unroll
        for (int j = 0; j < 4; ++j) {
            int ku = ((j * 2 + hi) ^ x7) * 8;
            bf16x8 kA0 = *(const bf16x8*)(kb + l31 * 64 + ku);
            bf16x8 kA1 = *(const bf16x8*)(kb + (32 + l31) * 64 + ku);
            bf16x8 qj = (j == 0) ? qB0 : (j == 1) ? qB1 : (j == 2) ? qB2 : qB3;
            st0 = MFMA32(kA0, qj, st0);
            st1 = MFMA32(kA1, qj, st1);
        }
        __builtin_amdgcn_s_setprio(0);

        // exp2 + in-register pack (v_perm truncation) + VALU row-sum partials
        union W4 { unsigned u[4]; bf16x8 v; };
        W4 wA0, wB0, wA1, wB1;
#pragma unroll
        for (int i2 = 0; i2 < 4; ++i2) {
            float a0 = __builtin_amdgcn_exp2f(st0[2 * i2]);
            float a1 = __builtin_amdgcn_exp2f(st0[2 * i2 + 1]);
            float a2 = __builtin_amdgcn_exp2f(st0[8 + 2 * i2]);
            float a3 = __builtin_amdgcn_exp2f(st0[9 + 2 * i2]);
            float b0 = __builtin_amdgcn_exp2f(st1[2 * i2]);
            float b1 = __builtin_amdgcn_exp2f(st1[2 * i2 + 1]);
            float b2 = __builtin_amdgcn_exp2f(st1[8 + 2 * i2]);
            float b3 = __builtin_amdgcn_exp2f(st1[9 + 2 * i2]);
            lsum += (a0 + a1) + (a2 + a3) + (b0 + b1) + (b2 + b3);
            wA0.u[i2] = __builtin_amdgcn_perm(fbits(a1), fbits(a0), 0x07060302);
            wB0.u[i2] = __builtin_amdgcn_perm(fbits(a3), fbits(a2), 0x07060302);
            wA1.u[i2] = __builtin_amdgcn_perm(fbits(b1), fbits(b0), 0x07060302);
            wB1.u[i2] = __builtin_amdgcn_perm(fbits(b3), fbits(b2), 0x07060302);
        }

        // PV: B-frag = single b128 at swizzled unit (2W+hi)^x7
        __builtin_amdgcn_s_setprio(1);
#pragma unroll
        for (int vt = 0; vt < 4; ++vt) {
            const unsigned short* vrow = vb + (vt * 32 + l31) * 64;
            o[vt] = MFMA32(wA0.v, *(const bf16x8*)(vrow + ((0 + hi) ^ x7) * 8), o[vt]);
            o[vt] = MFMA32(wB0.v, *(const bf16x8*)(vrow + ((2 + hi) ^ x7) * 8), o[vt]);
            o[vt] = MFMA32(wA1.v, *(const bf16x8*)(vrow + ((4 + hi) ^ x7) * 8), o[vt]);
            o[vt] = MFMA32(wB1.v, *(const bf16x8*)(vrow + ((6 + hi) ^ x7) * 8), o[vt]);
        }
        __builtin_amdgcn_s_setprio(0);

        // write-after-read protection: next iter's STAGE overwrites the buffer
        // we just computed from; all waves must be done with it first
        if (it + 1 < 8) __builtin_amdgcn_s_barrier();

        // swap buffers
        unsigned short* t;
        t = k0; k0 = k1; k1 = t;
        t = v0; v0 = v1; v1 = t;
    }

    int base = (b * 2 + comp) * 8 + split;
    unsigned short* op = Opart + (size_t)base * 4096 * 128;
#pragma unroll
    for (int vt = 0; vt < 4; ++vt)
#pragma unroll
        for (int r = 0; r < 16; ++r) {
            int qr = (r & 3) + 8 * (r >> 2) + 4 * hi;
            op[(size_t)(q0 + qr) * 128 + vt * 32 + l31] = f2bf(o[vt][r]);
        }
    // lane's lsum covers its 16 keys-half for q=q0+l31; add other half
    float ls = lsum + __shfl_xor(lsum, 32, 64);
    if (hi == 0)
        Lpart[(size_t)base * 4096 + q0 + l31] = ls;
}

// ---------------- Kernel 4: out = (SUM O1s)/l1 - lam * (SUM O2s)/l2 --------------
__global__ __launch_bounds__(256) void combine(const unsigned short* __restrict__ Opart,
        const float* __restrict__ Lpart, const float* __restrict__ lamp,
        float* __restrict__ out) {
    float lam = lamp[0];
    int i = blockIdx.x * 256 + threadIdx.x;   // float4 units over 2*4096*32
    int row = i >> 5;
    int c4  = i & 31;
    int b = row >> 12, q = row & 4095;

    float l1 = 0.f, l2 = 0.f;
#pragma unroll
    for (int s = 0; s < 8; ++s) {
        l1 += Lpart[((size_t)((b * 2 + 0) * 8 + s)) * 4096 + q];
        l2 += Lpart[((size_t)((b * 2 + 1) * 8 + s)) * 4096 + q];
    }
    float rl1 = 1.0f / l1, rl2 = 1.0f / l2;

    size_t qoff = (size_t)q * 128 + c4 * 4;
    float a0 = 0.f, a1 = 0.f, a2 = 0.f, a3 = 0.f;
    float c0 = 0.f, c1 = 0.f, c2 = 0.f, c3 = 0.f;
#pragma unroll
    for (int s = 0; s < 8; ++s) {
        ushort4 p1 = *(const ushort4*)(Opart + (size_t)((b * 2 + 0) * 8 + s) * 4096 * 128 + qoff);
        ushort4 p2 = *(const ushort4*)(Opart + (size_t)((b * 2 + 1) * 8 + s) * 4096 * 128 + qoff);
        a0 += bf2f(p1.x); a1 += bf2f(p1.y); a2 += bf2f(p1.z); a3 += bf2f(p1.w);
        c0 += bf2f(p2.x); c1 += bf2f(p2.y); c2 += bf2f(p2.z); c3 += bf2f(p2.w);
    }
    float4 r;
    r.x = a0 * rl1 - lam * c0 * rl2;
    r.y = a1 * rl1 - lam * c1 * rl2;
    r.z = a2 * rl1 - lam * c2 * rl2;
    r.w = a3 * rl1 - lam * c3 * rl2;
    ((float4*)out)[i] = r;
}

extern "C" void kernel_launch(void* const* d_in, const int* in_sizes, int n_in,
                              void* d_out, int out_size, void* d_ws, size_t ws_size,
                              hipStream_t stream) {
    const float* X   = (const float*)d_in[0];
    const float* Wq  = (const float*)d_in[1];
    const float* Wk  = (const float*)d_in[2];
    const float* Wv  = (const float*)d_in[3];
    const float* lam = (const float*)d_in[4];
    float* out = (float*)d_out;

    char* ws = (char*)d_ws;
    // Layout (Opart/Lpart alias WT+Xb: proj finishes before attn writes, same stream)
    unsigned short* Qc = (unsigned short*)(ws);                    // [2][2][4096][64]  2MB
    unsigned short* Kc = (unsigned short*)(ws + 2097152);          // [2][2][4096][64]  2MB
    unsigned short* VT = (unsigned short*)(ws + 4194304);          // [2][128][4096]    2MB
    unsigned short* WT = (unsigned short*)(ws + 6291456);          // 384x1024 bf16     768KB
    unsigned short* Xb = (unsigned short*)(ws + 7077888);          // 8192x1024 bf16    16MB
    unsigned short* Opart = (unsigned short*)(ws + 6291456);       // [32][4096][128] bf16 32MB (alias)
    float* Lpart = (float*)(ws + 39845888);                        // [32][4096] f32 512KB
    // end: 40,370,176 bytes

    prep_wt<<<dim3(96), dim3(256), 0, stream>>>(Wq, Wk, Wv, WT);
    prep_x<<<dim3(1024), dim3(256), 0, stream>>>(X, Xb);
    proj<<<dim3(128, 4), dim3(256), 0, stream>>>(Xb, WT, Qc, Kc, VT);
    attn<<<dim3(32, 2, 16), dim3(256), 0, stream>>>(Qc, Kc, VT, Opart, Lpart);
    combine<<<dim3(1024), dim3(256), 0, stream>>>(Opart, Lpart, lam, out);
}

// Round 13
// 70.591 us; speedup vs baseline: 1.1382x; 1.1382x over previous
//
#include <hip/hip_runtime.h>
#include <hip/hip_bf16.h>

typedef float f32x4 __attribute__((ext_vector_type(4)));
typedef float f32x16 __attribute__((ext_vector_type(16)));
typedef short bf16x8 __attribute__((ext_vector_type(8)));

#define MFMA16(A,B,C) __builtin_amdgcn_mfma_f32_16x16x32_bf16(A,B,C,0,0,0)
#define MFMA32(A,B,C) __builtin_amdgcn_mfma_f32_32x32x16_bf16(A,B,C,0,0,0)

__device__ __forceinline__ unsigned short f2bf(float f) {
    union { float f; unsigned u; } x; x.f = f;
    return (unsigned short)((x.u + 0x7FFFu + ((x.u >> 16) & 1u)) >> 16);
}

__device__ __forceinline__ float bf2f(unsigned short u) {
    union { unsigned u; float f; } x; x.u = ((unsigned)u) << 16; return x.f;
}

__device__ __forceinline__ unsigned fbits(float f) {
    union { float f; unsigned u; } x; x.f = f; return x.u;
}

__device__ __forceinline__ f32x16 zero16() {
    f32x16 z;
#pragma unroll
    for (int i = 0; i < 16; ++i) z[i] = 0.f;
    return z;
}

typedef const __attribute__((address_space(1))) unsigned int* as1_t;
typedef __attribute__((address_space(3))) unsigned int* as3_t;
__device__ __forceinline__ void gl_lds16(const unsigned short* g, unsigned short* l) {
    __builtin_amdgcn_global_load_lds((as1_t)g, (as3_t)l, 16, 0, 0);
}

// ---------------- Kernel 1: fused prep — WT transpose + X bf16 cast -------------
// blocks 0..95: WT[n][k] = W_cat[k][n]; blocks 96..1119: Xb = bf16(X)
__global__ __launch_bounds__(256) void prep(const float* __restrict__ Wq,
        const float* __restrict__ Wk, const float* __restrict__ Wv,
        const float* __restrict__ X, unsigned short* __restrict__ WT,
        unsigned short* __restrict__ Xb) {
    if (blockIdx.x < 96) {
        int w = blockIdx.x % 3;
        int kt = blockIdx.x / 3;       // 0..31
        const float* src = (w == 0) ? Wq : (w == 1) ? Wk : Wv;
        int k0 = kt * 32;
#pragma unroll
        for (int j = 0; j < 16; ++j) {
            int idx = threadIdx.x + j * 256;       // 0..4095
            int r = idx >> 7, c = idx & 127;
            float v = src[(size_t)(k0 + r) * 128 + c];
            WT[(size_t)(w * 128 + c) * 1024 + k0 + r] = f2bf(v);
        }
    } else {
        int i = (blockIdx.x - 96) * 256 + threadIdx.x;
#pragma unroll
        for (int r = 0; r < 8; ++r) {
            int idx = i + r * 262144;
            float4 x = ((const float4*)X)[idx];
            ushort4 p;
            p.x = f2bf(x.x); p.y = f2bf(x.y); p.z = f2bf(x.z); p.w = f2bf(x.w);
            ((ushort4*)Xb)[idx] = p;
        }
    }
}

// ---------------- Kernel 2: QKV projection, 3-buffer counted-vmcnt pipeline -----
// BM=64 (grid 128,4 = 512 blocks). V keys stored permuted:
// storage pos = (s & ~15) | swap23(s & 15), so attn PV B-frags are single b128.
__global__ __launch_bounds__(256) void proj(const unsigned short* __restrict__ Xb,
        const unsigned short* __restrict__ WT, unsigned short* __restrict__ Qc,
        unsigned short* __restrict__ Kc, unsigned short* __restrict__ VT) {
    int tid = threadIdx.x;
    int w = tid >> 6, lane = tid & 63;
    int lr = lane & 15, lg = lane >> 4;
    int wr = w >> 1, wc = w & 1;              // 2x2 wave grid
    int m0 = blockIdx.x * 64;
    int n0 = blockIdx.y * 96;

    __shared__ __align__(16) unsigned short Ab[3][64 * 64];   // 8KB x3
    __shared__ __align__(16) unsigned short Bb[3][96 * 64];   // 12KB x3

    f32x4 acc[2][3];
#pragma unroll
    for (int i = 0; i < 2; ++i)
#pragma unroll
        for (int j = 0; j < 3; ++j) acc[i][j] = f32x4{0.f,0.f,0.f,0.f};

    int srow = lane >> 3;
    int sunit = lane & 7;
    const unsigned short* aSrc = Xb + (size_t)(m0 + srow) * 1024 + sunit * 8;
    const unsigned short* bSrc = WT + (size_t)(n0 + srow) * 1024 + sunit * 8;

    auto STAGE = [&](unsigned short* ad, unsigned short* bd, int st) {
        int kk = st * 64;
#pragma unroll
        for (int i = 0; i < 2; ++i) {
            int blk = w * 2 + i;              // 0..7
            gl_lds16(aSrc + (size_t)blk * 8 * 1024 + kk, ad + blk * 512);
        }
#pragma unroll
        for (int i = 0; i < 3; ++i) {
            int blk = w * 3 + i;              // 0..11
            gl_lds16(bSrc + (size_t)blk * 8 * 1024 + kk, bd + blk * 512);
        }
    };

    unsigned short *a0 = Ab[0], *a1 = Ab[1], *a2 = Ab[2];
    unsigned short *b0 = Bb[0], *b1 = Bb[1], *b2 = Bb[2];
    STAGE(a0, b0, 0);
    STAGE(a1, b1, 1);

    for (int st = 0; st < 16; ++st) {
        // wait only for tile st (next tile's 5 loads stay in flight)
        if (st < 15) asm volatile("s_waitcnt vmcnt(5)" ::: "memory");
        else         asm volatile("s_waitcnt vmcnt(0)" ::: "memory");
        __builtin_amdgcn_sched_barrier(0);
        __builtin_amdgcn_s_barrier();
        __builtin_amdgcn_sched_barrier(0);
        if (st + 2 < 16) STAGE(a2, b2, st + 2);

        const unsigned short* ab = a0;
        const unsigned short* bb = b0;
#pragma unroll
        for (int ksub = 0; ksub < 2; ++ksub) {
            int ko = ksub * 32 + lg * 8;
            bf16x8 af[2], bf[3];
#pragma unroll
            for (int mt = 0; mt < 2; ++mt)
                af[mt] = *(const bf16x8*)(ab + (wr * 32 + mt * 16 + lr) * 64 + ko);
#pragma unroll
            for (int nt = 0; nt < 3; ++nt)
                bf[nt] = *(const bf16x8*)(bb + (wc * 48 + nt * 16 + lr) * 64 + ko);
#pragma unroll
            for (int mt = 0; mt < 2; ++mt)
#pragma unroll
                for (int nt = 0; nt < 3; ++nt)
                    acc[mt][nt] = MFMA16(af[mt], bf[nt], acc[mt][nt]);
        }
        // rotate buffers
        unsigned short* t;
        t = a0; a0 = a1; a1 = a2; a2 = t;
        t = b0; b0 = b1; b1 = b2; b2 = t;
    }

    int b = m0 >> 12;
    int sbase = (m0 & 4095) + wr * 32;
#pragma unroll
    for (int nt = 0; nt < 3; ++nt) {
        int gcol = n0 + wc * 48 + nt * 16 + lr;     // 0..383
        int tensor = gcol >> 7;                     // 0=Q 1=K 2=V
#pragma unroll
        for (int mt = 0; mt < 2; ++mt) {
            int sloc = sbase + mt * 16 + 4 * lg;
            if (tensor == 2) {
                int vcol = gcol & 127;
                // key-permuted storage: 4-key group lg -> group swap(lg bits)
                int slocV = (sloc & ~15) | (((lg & 1) << 3) | ((lg >> 1) << 2));
                ushort4 pk;
                pk.x = f2bf(acc[mt][nt][0]); pk.y = f2bf(acc[mt][nt][1]);
                pk.z = f2bf(acc[mt][nt][2]); pk.w = f2bf(acc[mt][nt][3]);
                *(ushort4*)(VT + (size_t)(b * 128 + vcol) * 4096 + slocV) = pk;
            } else {
                int within = gcol & 127;
                int comp = within >> 6;
                int col64 = within & 63;
                float sc = (tensor == 0) ? 0.1803368801f : 1.0f;  // (1/8)*log2e in Q
                unsigned short* dst = (tensor == 0) ? Qc : Kc;
                size_t rowb = (size_t)(comp * 2 + b) * 4096 + sloc;
#pragma unroll
                for (int r = 0; r < 4; ++r)
                    dst[(rowb + r) * 64 + col64] = f2bf(acc[mt][nt][r] * sc);
            }
        }
    }
}

// ---------------- Kernel 3: flash attention, R11 structure, VALU row-sums -------
// 32q/wave x 128v, swapped QK^T, in-register softmax (v_perm pack), key-permuted
// V (bank-conflict-free b128 PV reads). 3-buffer counted-vmcnt pipeline. bf16
// partials, 4 k-splits.
__global__ __launch_bounds__(256, 2) void attn(const unsigned short* __restrict__ Qc,
        const unsigned short* __restrict__ Kc, const unsigned short* __restrict__ VT,
        unsigned short* __restrict__ Opart, float* __restrict__ Lpart) {
    int tid = threadIdx.x;
    int wave = tid >> 6, lane = tid & 63;
    int l31 = lane & 31, hi = lane >> 5;
    int x7 = l31 & 7;
    int b = blockIdx.y;
    int comp = blockIdx.z >> 2, split = blockIdx.z & 3;
    int q0 = blockIdx.x * 128 + wave * 32;
    int kstart = split * 1024;

    __shared__ __align__(16) unsigned short kb3[3][64 * 64];    // 8KB x3
    __shared__ __align__(16) unsigned short vb3[3][128 * 64];   // 16KB x3

    // Q B-frags: lane holds col q = q0+l31, d = j*16 + hi*8 + e
    const unsigned short* Qp = Qc + ((size_t)(comp * 2 + b) * 4096 + q0 + l31) * 64 + hi * 8;
    bf16x8 qB0 = *(const bf16x8*)(Qp);
    bf16x8 qB1 = *(const bf16x8*)(Qp + 16);
    bf16x8 qB2 = *(const bf16x8*)(Qp + 32);
    bf16x8 qB3 = *(const bf16x8*)(Qp + 48);

    f32x16 o[4];
#pragma unroll
    for (int i = 0; i < 4; ++i) o[i] = zero16();
    float lsum = 0.f;

    const unsigned short* kSrc = Kc + ((size_t)(comp * 2 + b) * 4096 + kstart
                                       + wave * 8 + (lane >> 3)) * 64
                                    + ((lane & 7) ^ (lane >> 3)) * 8;
    const unsigned short* vSrc = VT + ((size_t)b * 128 + (tid >> 3)) * 4096
                                    + kstart + ((lane & 7) ^ (lane >> 3)) * 8;

    auto STAGE = [&](unsigned short* kd, unsigned short* vd, int it) {
        const unsigned short* ks = kSrc + (size_t)it * 4096;
        gl_lds16(ks,        kd + wave * 512);
        gl_lds16(ks + 2048, kd + 2048 + wave * 512);
        const unsigned short* vs = vSrc + it * 64;
#pragma unroll
        for (int ri = 0; ri < 4; ++ri)
            gl_lds16(vs + (size_t)ri * 32 * 4096, vd + ri * 2048 + wave * 512);
    };

    unsigned short *k0 = kb3[0], *k1 = kb3[1], *k2 = kb3[2];
    unsigned short *v0 = vb3[0], *v1 = vb3[1], *v2 = vb3[2];
    STAGE(k0, v0, 0);
    STAGE(k1, v1, 1);

    for (int it = 0; it < 16; ++it) {
        // wait for tile it only; tile it+1's 6 loads stay in flight across barrier
        if (it < 15) asm volatile("s_waitcnt vmcnt(6)" ::: "memory");
        else         asm volatile("s_waitcnt vmcnt(0)" ::: "memory");
        __builtin_amdgcn_sched_barrier(0);
        __builtin_amdgcn_s_barrier();
        __builtin_amdgcn_sched_barrier(0);
        if (it + 2 < 16) STAGE(k2, v2, it + 2);

        const unsigned short* kb = k0;
        const unsigned short* vb = v0;

        // S^T[k][q] for two 32-key half-tiles: A = K rows, B = Q cols
        f32x16 st0 = zero16(), st1 = zero16();
        __builtin_amdgcn_s_setprio(1);
#pragma unroll
        for (int j = 0; j < 4; ++j) {
            int ku = ((j * 2 + hi) ^ x7) * 8;
            bf16x8 kA0 = *(const bf16x8*)(kb + l31 * 64 + ku);
            bf16x8 kA1 = *(const bf16x8*)(kb + (32 + l31) * 64 + ku);
            bf16x8 qj = (j == 0) ? qB0 : (j == 1) ? qB1 : (j == 2) ? qB2 : qB3;
            st0 = MFMA32(kA0, qj, st0);
            st1 = MFMA32(kA1, qj, st1);
        }
        __builtin_amdgcn_s_setprio(0);

        // exp2 + in-register pack (v_perm truncation) + VALU row-sum partials
        union W4 { unsigned u[4]; bf16x8 v; };
        W4 wA0, wB0, wA1, wB1;
#pragma unroll
        for (int i2 = 0; i2 < 4; ++i2) {
            float a0 = __builtin_amdgcn_exp2f(st0[2 * i2]);
            float a1 = __builtin_amdgcn_exp2f(st0[2 * i2 + 1]);
            float a2 = __builtin_amdgcn_exp2f(st0[8 + 2 * i2]);
            float a3 = __builtin_amdgcn_exp2f(st0[9 + 2 * i2]);
            float b0 = __builtin_amdgcn_exp2f(st1[2 * i2]);
            float b1 = __builtin_amdgcn_exp2f(st1[2 * i2 + 1]);
            float b2 = __builtin_amdgcn_exp2f(st1[8 + 2 * i2]);
            float b3 = __builtin_amdgcn_exp2f(st1[9 + 2 * i2]);
            lsum += (a0 + a1) + (a2 + a3) + (b0 + b1) + (b2 + b3);
            wA0.u[i2] = __builtin_amdgcn_perm(fbits(a1), fbits(a0), 0x07060302);
            wB0.u[i2] = __builtin_amdgcn_perm(fbits(a3), fbits(a2), 0x07060302);
            wA1.u[i2] = __builtin_amdgcn_perm(fbits(b1), fbits(b0), 0x07060302);
            wB1.u[i2] = __builtin_amdgcn_perm(fbits(b3), fbits(b2), 0x07060302);
        }

        // PV: B-frag = single b128 at swizzled unit (2W+hi)^x7
        __builtin_amdgcn_s_setprio(1);
#pragma unroll
        for (int vt = 0; vt < 4; ++vt) {
            const unsigned short* vrow = vb + (vt * 32 + l31) * 64;
            o[vt] = MFMA32(wA0.v, *(const bf16x8*)(vrow + ((0 + hi) ^ x7) * 8), o[vt]);
            o[vt] = MFMA32(wB0.v, *(const bf16x8*)(vrow + ((2 + hi) ^ x7) * 8), o[vt]);
            o[vt] = MFMA32(wA1.v, *(const bf16x8*)(vrow + ((4 + hi) ^ x7) * 8), o[vt]);
            o[vt] = MFMA32(wB1.v, *(const bf16x8*)(vrow + ((6 + hi) ^ x7) * 8), o[vt]);
        }
        __builtin_amdgcn_s_setprio(0);

        // rotate buffers
        unsigned short* t;
        t = k0; k0 = k1; k1 = k2; k2 = t;
        t = v0; v0 = v1; v1 = v2; v2 = t;
    }

    int base = (b * 2 + comp) * 4 + split;
    unsigned short* op = Opart + (size_t)base * 4096 * 128;
#pragma unroll
    for (int vt = 0; vt < 4; ++vt)
#pragma unroll
        for (int r = 0; r < 16; ++r) {
            int qr = (r & 3) + 8 * (r >> 2) + 4 * hi;
            op[(size_t)(q0 + qr) * 128 + vt * 32 + l31] = f2bf(o[vt][r]);
        }
    // lane's lsum covers 32 of 64 keys/tile for q=q0+l31; other half is at hi^1
    float ls = lsum + __shfl_xor(lsum, 32, 64);
    if (hi == 0)
        Lpart[(size_t)base * 4096 + q0 + l31] = ls;
}

// ---------------- Kernel 4: out = (SUM O1s)/l1 - lam * (SUM O2s)/l2 --------------
__global__ __launch_bounds__(256) void combine(const unsigned short* __restrict__ Opart,
        const float* __restrict__ Lpart, const float* __restrict__ lamp,
        float* __restrict__ out) {
    float lam = lamp[0];
    int i = blockIdx.x * 256 + threadIdx.x;   // float4 units over 2*4096*32
    int row = i >> 5;
    int c4  = i & 31;
    int b = row >> 12, q = row & 4095;

    float l1 = 0.f, l2 = 0.f;
#pragma unroll
    for (int s = 0; s < 4; ++s) {
        l1 += Lpart[((size_t)((b * 2 + 0) * 4 + s)) * 4096 + q];
        l2 += Lpart[((size_t)((b * 2 + 1) * 4 + s)) * 4096 + q];
    }
    float rl1 = 1.0f / l1, rl2 = 1.0f / l2;

    size_t qoff = (size_t)q * 128 + c4 * 4;
    float a0 = 0.f, a1 = 0.f, a2 = 0.f, a3 = 0.f;
    float c0 = 0.f, c1 = 0.f, c2 = 0.f, c3 = 0.f;
#pragma unroll
    for (int s = 0; s < 4; ++s) {
        ushort4 p1 = *(const ushort4*)(Opart + (size_t)((b * 2 + 0) * 4 + s) * 4096 * 128 + qoff);
        ushort4 p2 = *(const ushort4*)(Opart + (size_t)((b * 2 + 1) * 4 + s) * 4096 * 128 + qoff);
        a0 += bf2f(p1.x); a1 += bf2f(p1.y); a2 += bf2f(p1.z); a3 += bf2f(p1.w);
        c0 += bf2f(p2.x); c1 += bf2f(p2.y); c2 += bf2f(p2.z); c3 += bf2f(p2.w);
    }
    float4 r;
    r.x = a0 * rl1 - lam * c0 * rl2;
    r.y = a1 * rl1 - lam * c1 * rl2;
    r.z = a2 * rl1 - lam * c2 * rl2;
    r.w = a3 * rl1 - lam * c3 * rl2;
    ((float4*)out)[i] = r;
}

extern "C" void kernel_launch(void* const* d_in, const int* in_sizes, int n_in,
                              void* d_out, int out_size, void* d_ws, size_t ws_size,
                              hipStream_t stream) {
    const float* X   = (const float*)d_in[0];
    const float* Wq  = (const float*)d_in[1];
    const float* Wk  = (const float*)d_in[2];
    const float* Wv  = (const float*)d_in[3];
    const float* lam = (const float*)d_in[4];
    float* out = (float*)d_out;

    char* ws = (char*)d_ws;
    // Layout (Opart/Lpart alias WT+Xb: proj finishes before attn writes, same stream)
    unsigned short* Qc = (unsigned short*)(ws);                    // [2][2][4096][64]  2MB
    unsigned short* Kc = (unsigned short*)(ws + 2097152);          // [2][2][4096][64]  2MB
    unsigned short* VT = (unsigned short*)(ws + 4194304);          // [2][128][4096]    2MB
    unsigned short* WT = (unsigned short*)(ws + 6291456);          // 384x1024 bf16     768KB
    unsigned short* Xb = (unsigned short*)(ws + 7077888);          // 8192x1024 bf16    16MB
    unsigned short* Opart = (unsigned short*)(ws + 6291456);       // [16][4096][128] bf16 16MB (alias)
    float* Lpart = (float*)(ws + 23068672);                        // [16][4096] f32 256KB (alias)
    // end of distinct region: 23855104 bytes

    prep<<<dim3(1120), dim3(256), 0, stream>>>(Wq, Wk, Wv, X, WT, Xb);
    proj<<<dim3(128, 4), dim3(256), 0, stream>>>(Xb, WT, Qc, Kc, VT);
    attn<<<dim3(32, 2, 8), dim3(256), 0, stream>>>(Qc, Kc, VT, Opart, Lpart);
    combine<<<dim3(1024), dim3(256), 0, stream>>>(Opart, Lpart, lam, out);
}

// Round 14
// 66.688 us; speedup vs baseline: 1.2048x; 1.0585x over previous
//
#include <hip/hip_runtime.h>
#include <hip/hip_bf16.h>

typedef float f32x4 __attribute__((ext_vector_type(4)));
typedef float f32x16 __attribute__((ext_vector_type(16)));
typedef short bf16x8 __attribute__((ext_vector_type(8)));

#define MFMA16(A,B,C) __builtin_amdgcn_mfma_f32_16x16x32_bf16(A,B,C,0,0,0)
#define MFMA32(A,B,C) __builtin_amdgcn_mfma_f32_32x32x16_bf16(A,B,C,0,0,0)

__device__ __forceinline__ unsigned short f2bf(float f) {
    union { float f; unsigned u; } x; x.f = f;
    return (unsigned short)((x.u + 0x7FFFu + ((x.u >> 16) & 1u)) >> 16);
}

__device__ __forceinline__ float bf2f(unsigned short u) {
    union { unsigned u; float f; } x; x.u = ((unsigned)u) << 16; return x.f;
}

__device__ __forceinline__ unsigned fbits(float f) {
    union { float f; unsigned u; } x; x.f = f; return x.u;
}

__device__ __forceinline__ f32x16 zero16() {
    f32x16 z;
#pragma unroll
    for (int i = 0; i < 16; ++i) z[i] = 0.f;
    return z;
}

typedef const __attribute__((address_space(1))) unsigned int* as1_t;
typedef __attribute__((address_space(3))) unsigned int* as3_t;
__device__ __forceinline__ void gl_lds16(const unsigned short* g, unsigned short* l) {
    __builtin_amdgcn_global_load_lds((as1_t)g, (as3_t)l, 16, 0, 0);
}

// ---------------- Kernel 1: WT[n][k] = W_cat[k][n] bf16, coalesced reads --------
__global__ __launch_bounds__(256) void prep(const float* __restrict__ Wq,
        const float* __restrict__ Wk, const float* __restrict__ Wv,
        unsigned short* __restrict__ WT) {
    int w = blockIdx.x % 3;
    int kt = blockIdx.x / 3;       // 0..31
    const float* src = (w == 0) ? Wq : (w == 1) ? Wk : Wv;
    int k0 = kt * 32;
#pragma unroll
    for (int j = 0; j < 16; ++j) {
        int idx = threadIdx.x + j * 256;       // 0..4095
        int r = idx >> 7, c = idx & 127;
        float v = src[(size_t)(k0 + r) * 128 + c];
        WT[(size_t)(w * 128 + c) * 1024 + k0 + r] = f2bf(v);
    }
}

// ---------------- Kernel 2: QKV projection, A reg-staged from X f32 -------------
// BM=64 (grid 128,4 = 512 blocks). A-tile converted f32->bf16 in flight (no
// separate X-cast kernel); B staged via global_load_lds. 3-buffer pipeline.
// V keys stored permuted: pos = (s & ~15) | swap23(s & 15) for attn b128 PV.
__global__ __launch_bounds__(256) void proj(const float* __restrict__ Xf,
        const unsigned short* __restrict__ WT, unsigned short* __restrict__ Qc,
        unsigned short* __restrict__ Kc, unsigned short* __restrict__ VT) {
    int tid = threadIdx.x;
    int w = tid >> 6, lane = tid & 63;
    int lr = lane & 15, lg = lane >> 4;
    int wr = w >> 1, wc = w & 1;              // 2x2 wave grid
    int m0 = blockIdx.x * 64;
    int n0 = blockIdx.y * 96;

    __shared__ __align__(16) unsigned short Ab[3][64 * 64];   // 8KB x3
    __shared__ __align__(16) unsigned short Bb[3][96 * 64];   // 12KB x3

    f32x4 acc[2][3];
#pragma unroll
    for (int i = 0; i < 2; ++i)
#pragma unroll
        for (int j = 0; j < 3; ++j) acc[i][j] = f32x4{0.f,0.f,0.f,0.f};

    int srow = lane >> 3;
    int sunit = lane & 7;
    const unsigned short* bSrc = WT + (size_t)(n0 + srow) * 1024 + sunit * 8;

    // A reg-staging: thread t covers float4 chunks f = t + i*256 of the
    // 64x64 f32 tile; row = f>>4, col4 = f&15 (16 float4 per row).
    float4 aReg[4];
    auto A_LOAD = [&](int st) {
        int kk = st * 64;
#pragma unroll
        for (int i = 0; i < 4; ++i) {
            int f = tid + i * 256;
            int row = f >> 4, c4 = f & 15;
            aReg[i] = *(const float4*)(Xf + (size_t)(m0 + row) * 1024 + kk + c4 * 4);
        }
    };
    auto A_WRITE = [&](unsigned short* ad) {
#pragma unroll
        for (int i = 0; i < 4; ++i) {
            int f = tid + i * 256;
            int row = f >> 4, c4 = f & 15;
            ushort4 pk;
            pk.x = f2bf(aReg[i].x); pk.y = f2bf(aReg[i].y);
            pk.z = f2bf(aReg[i].z); pk.w = f2bf(aReg[i].w);
            *(ushort4*)(ad + row * 64 + c4 * 4) = pk;
        }
    };
    auto B_STAGE = [&](unsigned short* bd, int st) {
        int kk = st * 64;
#pragma unroll
        for (int i = 0; i < 3; ++i) {
            int blk = w * 3 + i;              // 0..11
            gl_lds16(bSrc + (size_t)blk * 8 * 1024 + kk, bd + blk * 512);
        }
    };

    unsigned short *a0 = Ab[0], *a1 = Ab[1], *a2 = Ab[2];
    unsigned short *b0 = Bb[0], *b1 = Bb[1], *b2 = Bb[2];
    // prologue: A0,B0 then A1,B1; A_WRITE drains its loads (and older B's)
    A_LOAD(0); B_STAGE(b0, 0);
    A_WRITE(a0);
    A_LOAD(1); B_STAGE(b1, 1);
    A_WRITE(a1);

    for (int st = 0; st < 16; ++st) {
        // B(st) is older than A(st+1) whose A_WRITE already drained it;
        // ds_writes of A(st+1) must be visible -> lgkmcnt(0) before barrier.
        if (st < 15) asm volatile("s_waitcnt vmcnt(3) lgkmcnt(0)" ::: "memory");
        else         asm volatile("s_waitcnt vmcnt(0) lgkmcnt(0)" ::: "memory");
        __builtin_amdgcn_sched_barrier(0);
        __builtin_amdgcn_s_barrier();
        __builtin_amdgcn_sched_barrier(0);
        if (st + 2 < 16) { A_LOAD(st + 2); B_STAGE(b2, st + 2); }

        const unsigned short* ab = a0;
        const unsigned short* bb = b0;
#pragma unroll
        for (int ksub = 0; ksub < 2; ++ksub) {
            int ko = ksub * 32 + lg * 8;
            bf16x8 af[2], bf[3];
#pragma unroll
            for (int mt = 0; mt < 2; ++mt)
                af[mt] = *(const bf16x8*)(ab + (wr * 32 + mt * 16 + lr) * 64 + ko);
#pragma unroll
            for (int nt = 0; nt < 3; ++nt)
                bf[nt] = *(const bf16x8*)(bb + (wc * 48 + nt * 16 + lr) * 64 + ko);
#pragma unroll
            for (int mt = 0; mt < 2; ++mt)
#pragma unroll
                for (int nt = 0; nt < 3; ++nt)
                    acc[mt][nt] = MFMA16(af[mt], bf[nt], acc[mt][nt]);
        }
        if (st + 2 < 16) A_WRITE(a2);   // compiler waits aReg loads here

        // rotate buffers
        unsigned short* t;
        t = a0; a0 = a1; a1 = a2; a2 = t;
        t = b0; b0 = b1; b1 = b2; b2 = t;
    }

    int b = m0 >> 12;
    int sbase = (m0 & 4095) + wr * 32;
#pragma unroll
    for (int nt = 0; nt < 3; ++nt) {
        int gcol = n0 + wc * 48 + nt * 16 + lr;     // 0..383
        int tensor = gcol >> 7;                     // 0=Q 1=K 2=V
#pragma unroll
        for (int mt = 0; mt < 2; ++mt) {
            int sloc = sbase + mt * 16 + 4 * lg;
            if (tensor == 2) {
                int vcol = gcol & 127;
                // key-permuted storage: 4-key group lg -> group swap(lg bits)
                int slocV = (sloc & ~15) | (((lg & 1) << 3) | ((lg >> 1) << 2));
                ushort4 pk;
                pk.x = f2bf(acc[mt][nt][0]); pk.y = f2bf(acc[mt][nt][1]);
                pk.z = f2bf(acc[mt][nt][2]); pk.w = f2bf(acc[mt][nt][3]);
                *(ushort4*)(VT + (size_t)(b * 128 + vcol) * 4096 + slocV) = pk;
            } else {
                int within = gcol & 127;
                int comp = within >> 6;
                int col64 = within & 63;
                float sc = (tensor == 0) ? 0.1803368801f : 1.0f;  // (1/8)*log2e in Q
                unsigned short* dst = (tensor == 0) ? Qc : Kc;
                size_t rowb = (size_t)(comp * 2 + b) * 4096 + sloc;
#pragma unroll
                for (int r = 0; r < 4; ++r)
                    dst[(rowb + r) * 64 + col64] = f2bf(acc[mt][nt][r] * sc);
            }
        }
    }
}

// ---------------- Kernel 3: flash attention, R11 structure, VALU row-sums -------
// 32q/wave x 128v, swapped QK^T, in-register softmax (v_perm pack), key-permuted
// V (bank-conflict-free b128 PV reads). 3-buffer counted-vmcnt pipeline. bf16
// partials, 4 k-splits.
__global__ __launch_bounds__(256, 2) void attn(const unsigned short* __restrict__ Qc,
        const unsigned short* __restrict__ Kc, const unsigned short* __restrict__ VT,
        unsigned short* __restrict__ Opart, float* __restrict__ Lpart) {
    int tid = threadIdx.x;
    int wave = tid >> 6, lane = tid & 63;
    int l31 = lane & 31, hi = lane >> 5;
    int x7 = l31 & 7;
    int b = blockIdx.y;
    int comp = blockIdx.z >> 2, split = blockIdx.z & 3;
    int q0 = blockIdx.x * 128 + wave * 32;
    int kstart = split * 1024;

    __shared__ __align__(16) unsigned short kb3[3][64 * 64];    // 8KB x3
    __shared__ __align__(16) unsigned short vb3[3][128 * 64];   // 16KB x3

    // Q B-frags: lane holds col q = q0+l31, d = j*16 + hi*8 + e
    const unsigned short* Qp = Qc + ((size_t)(comp * 2 + b) * 4096 + q0 + l31) * 64 + hi * 8;
    bf16x8 qB0 = *(const bf16x8*)(Qp);
    bf16x8 qB1 = *(const bf16x8*)(Qp + 16);
    bf16x8 qB2 = *(const bf16x8*)(Qp + 32);
    bf16x8 qB3 = *(const bf16x8*)(Qp + 48);

    f32x16 o[4];
#pragma unroll
    for (int i = 0; i < 4; ++i) o[i] = zero16();
    float lsum = 0.f;

    const unsigned short* kSrc = Kc + ((size_t)(comp * 2 + b) * 4096 + kstart
                                       + wave * 8 + (lane >> 3)) * 64
                                    + ((lane & 7) ^ (lane >> 3)) * 8;
    const unsigned short* vSrc = VT + ((size_t)b * 128 + (tid >> 3)) * 4096
                                    + kstart + ((lane & 7) ^ (lane >> 3)) * 8;

    auto STAGE = [&](unsigned short* kd, unsigned short* vd, int it) {
        const unsigned short* ks = kSrc + (size_t)it * 4096;
        gl_lds16(ks,        kd + wave * 512);
        gl_lds16(ks + 2048, kd + 2048 + wave * 512);
        const unsigned short* vs = vSrc + it * 64;
#pragma unroll
        for (int ri = 0; ri < 4; ++ri)
            gl_lds16(vs + (size_t)ri * 32 * 4096, vd + ri * 2048 + wave * 512);
    };

    unsigned short *k0 = kb3[0], *k1 = kb3[1], *k2 = kb3[2];
    unsigned short *v0 = vb3[0], *v1 = vb3[1], *v2 = vb3[2];
    STAGE(k0, v0, 0);
    STAGE(k1, v1, 1);

    for (int it = 0; it < 16; ++it) {
        // wait for tile it only; tile it+1's 6 loads stay in flight across barrier
        if (it < 15) asm volatile("s_waitcnt vmcnt(6)" ::: "memory");
        else         asm volatile("s_waitcnt vmcnt(0)" ::: "memory");
        __builtin_amdgcn_sched_barrier(0);
        __builtin_amdgcn_s_barrier();
        __builtin_amdgcn_sched_barrier(0);
        if (it + 2 < 16) STAGE(k2, v2, it + 2);

        const unsigned short* kb = k0;
        const unsigned short* vb = v0;

        // S^T[k][q] for two 32-key half-tiles: A = K rows, B = Q cols
        f32x16 st0 = zero16(), st1 = zero16();
        __builtin_amdgcn_s_setprio(1);
#pragma unroll
        for (int j = 0; j < 4; ++j) {
            int ku = ((j * 2 + hi) ^ x7) * 8;
            bf16x8 kA0 = *(const bf16x8*)(kb + l31 * 64 + ku);
            bf16x8 kA1 = *(const bf16x8*)(kb + (32 + l31) * 64 + ku);
            bf16x8 qj = (j == 0) ? qB0 : (j == 1) ? qB1 : (j == 2) ? qB2 : qB3;
            st0 = MFMA32(kA0, qj, st0);
            st1 = MFMA32(kA1, qj, st1);
        }
        __builtin_amdgcn_s_setprio(0);

        // exp2 + in-register pack (v_perm truncation) + VALU row-sum partials
        union W4 { unsigned u[4]; bf16x8 v; };
        W4 wA0, wB0, wA1, wB1;
#pragma unroll
        for (int i2 = 0; i2 < 4; ++i2) {
            float a0 = __builtin_amdgcn_exp2f(st0[2 * i2]);
            float a1 = __builtin_amdgcn_exp2f(st0[2 * i2 + 1]);
            float a2 = __builtin_amdgcn_exp2f(st0[8 + 2 * i2]);
            float a3 = __builtin_amdgcn_exp2f(st0[9 + 2 * i2]);
            float b0 = __builtin_amdgcn_exp2f(st1[2 * i2]);
            float b1 = __builtin_amdgcn_exp2f(st1[2 * i2 + 1]);
            float b2 = __builtin_amdgcn_exp2f(st1[8 + 2 * i2]);
            float b3 = __builtin_amdgcn_exp2f(st1[9 + 2 * i2]);
            lsum += (a0 + a1) + (a2 + a3) + (b0 + b1) + (b2 + b3);
            wA0.u[i2] = __builtin_amdgcn_perm(fbits(a1), fbits(a0), 0x07060302);
            wB0.u[i2] = __builtin_amdgcn_perm(fbits(a3), fbits(a2), 0x07060302);
            wA1.u[i2] = __builtin_amdgcn_perm(fbits(b1), fbits(b0), 0x07060302);
            wB1.u[i2] = __builtin_amdgcn_perm(fbits(b3), fbits(b2), 0x07060302);
        }

        // PV: B-frag = single b128 at swizzled unit (2W+hi)^x7
        __builtin_amdgcn_s_setprio(1);
#pragma unroll
        for (int vt = 0; vt < 4; ++vt) {
            const unsigned short* vrow = vb + (vt * 32 + l31) * 64;
            o[vt] = MFMA32(wA0.v, *(const bf16x8*)(vrow + ((0 + hi) ^ x7) * 8), o[vt]);
            o[vt] = MFMA32(wB0.v, *(const bf16x8*)(vrow + ((2 + hi) ^ x7) * 8), o[vt]);
            o[vt] = MFMA32(wA1.v, *(const bf16x8*)(vrow + ((4 + hi) ^ x7) * 8), o[vt]);
            o[vt] = MFMA32(wB1.v, *(const bf16x8*)(vrow + ((6 + hi) ^ x7) * 8), o[vt]);
        }
        __builtin_amdgcn_s_setprio(0);

        // rotate buffers
        unsigned short* t;
        t = k0; k0 = k1; k1 = k2; k2 = t;
        t = v0; v0 = v1; v1 = v2; v2 = t;
    }

    int base = (b * 2 + comp) * 4 + split;
    unsigned short* op = Opart + (size_t)base * 4096 * 128;
#pragma unroll
    for (int vt = 0; vt < 4; ++vt)
#pragma unroll
        for (int r = 0; r < 16; ++r) {
            int qr = (r & 3) + 8 * (r >> 2) + 4 * hi;
            op[(size_t)(q0 + qr) * 128 + vt * 32 + l31] = f2bf(o[vt][r]);
        }
    // lane's lsum covers 32 of 64 keys/tile for q=q0+l31; other half is at hi^1
    float ls = lsum + __shfl_xor(lsum, 32, 64);
    if (hi == 0)
        Lpart[(size_t)base * 4096 + q0 + l31] = ls;
}

// ---------------- Kernel 4: out = (SUM O1s)/l1 - lam * (SUM O2s)/l2 --------------
__global__ __launch_bounds__(256) void combine(const unsigned short* __restrict__ Opart,
        const float* __restrict__ Lpart, const float* __restrict__ lamp,
        float* __restrict__ out) {
    float lam = lamp[0];
    int i = blockIdx.x * 256 + threadIdx.x;   // float4 units over 2*4096*32
    int row = i >> 5;
    int c4  = i & 31;
    int b = row >> 12, q = row & 4095;

    float l1 = 0.f, l2 = 0.f;
#pragma unroll
    for (int s = 0; s < 4; ++s) {
        l1 += Lpart[((size_t)((b * 2 + 0) * 4 + s)) * 4096 + q];
        l2 += Lpart[((size_t)((b * 2 + 1) * 4 + s)) * 4096 + q];
    }
    float rl1 = 1.0f / l1, rl2 = 1.0f / l2;

    size_t qoff = (size_t)q * 128 + c4 * 4;
    float a0 = 0.f, a1 = 0.f, a2 = 0.f, a3 = 0.f;
    float c0 = 0.f, c1 = 0.f, c2 = 0.f, c3 = 0.f;
#pragma unroll
    for (int s = 0; s < 4; ++s) {
        ushort4 p1 = *(const ushort4*)(Opart + (size_t)((b * 2 + 0) * 4 + s) * 4096 * 128 + qoff);
        ushort4 p2 = *(const ushort4*)(Opart + (size_t)((b * 2 + 1) * 4 + s) * 4096 * 128 + qoff);
        a0 += bf2f(p1.x); a1 += bf2f(p1.y); a2 += bf2f(p1.z); a3 += bf2f(p1.w);
        c0 += bf2f(p2.x); c1 += bf2f(p2.y); c2 += bf2f(p2.z); c3 += bf2f(p2.w);
    }
    float4 r;
    r.x = a0 * rl1 - lam * c0 * rl2;
    r.y = a1 * rl1 - lam * c1 * rl2;
    r.z = a2 * rl1 - lam * c2 * rl2;
    r.w = a3 * rl1 - lam * c3 * rl2;
    ((float4*)out)[i] = r;
}

extern "C" void kernel_launch(void* const* d_in, const int* in_sizes, int n_in,
                              void* d_out, int out_size, void* d_ws, size_t ws_size,
                              hipStream_t stream) {
    const float* X   = (const float*)d_in[0];
    const float* Wq  = (const float*)d_in[1];
    const float* Wk  = (const float*)d_in[2];
    const float* Wv  = (const float*)d_in[3];
    const float* lam = (const float*)d_in[4];
    float* out = (float*)d_out;

    char* ws = (char*)d_ws;
    // Layout (Opart/Lpart alias WT: proj finishes before attn writes, same stream)
    unsigned short* Qc = (unsigned short*)(ws);                    // [2][2][4096][64]  2MB
    unsigned short* Kc = (unsigned short*)(ws + 2097152);          // [2][2][4096][64]  2MB
    unsigned short* VT = (unsigned short*)(ws + 4194304);          // [2][128][4096]    2MB
    unsigned short* WT = (unsigned short*)(ws + 6291456);          // 384x1024 bf16     768KB
    unsigned short* Opart = (unsigned short*)(ws + 6291456);       // [16][4096][128] bf16 16MB (alias)
    float* Lpart = (float*)(ws + 23068672);                        // [16][4096] f32 256KB (alias)
    // end of distinct region: 23855104 bytes

    prep<<<dim3(96), dim3(256), 0, stream>>>(Wq, Wk, Wv, WT);
    proj<<<dim3(128, 4), dim3(256), 0, stream>>>(X, WT, Qc, Kc, VT);
    attn<<<dim3(32, 2, 8), dim3(256), 0, stream>>>(Qc, Kc, VT, Opart, Lpart);
    combine<<<dim3(1024), dim3(256), 0, stream>>>(Opart, Lpart, lam, out);
}